// Round 7
// baseline (140.255 us; speedup 1.0000x reference)
//
#include <hip/hip_runtime.h>
#include <cstdint>
#include <cstddef>

typedef __bf16 bf16;
typedef __attribute__((ext_vector_type(4))) __bf16 bf16x4;
typedef __attribute__((ext_vector_type(8))) __bf16 bf16x8;
typedef __attribute__((ext_vector_type(4))) float f32x4;

#define EPS_C 1e-4f
#define SWZ(r) (((r) ^ ((r) >> 2)) & 3)

// light barrier: LDS visibility only, vmem loads stay in flight (no vmcnt drain)
#define BAR_LDS() do { asm volatile("s_waitcnt lgkmcnt(0)" ::: "memory"); \
                       __builtin_amdgcn_s_barrier(); } while (0)

// ================= K0: weights prep + zero page =================
__global__ __launch_bounds__(256) void k0_prep(const float* __restrict__ Wi,
    const float* __restrict__ Wo, bf16* __restrict__ Whg, bf16* __restrict__ Wlg,
    bf16* __restrict__ Wob, float* __restrict__ zpg)
{
    int idx = blockIdx.x * 256 + threadIdx.x;
    if (idx < 192 * 1024) {
        int n = idx >> 10, k = idx & 1023;
        float w;
        if (n < 64) {
            w = Wi[n * 1024 + k];
        } else if (n < 128) {
            int i = n - 64;
            w = 0.5f * (Wi[(64 + 2 * i) * 1024 + k] + Wi[(65 + 2 * i) * 1024 + k]);
        } else {
            int i = n - 128;
            w = 0.5f * (Wi[(192 + 2 * i) * 1024 + k] + Wi[(193 + 2 * i) * 1024 + k]);
        }
        bf16 h = (bf16)w;
        int dst = (k >> 5) * 6144 + n * 32 + (k & 31);
        Whg[dst] = h;
        Wlg[dst] = (bf16)(w - (float)h);
    } else if (idx < 262144) {
        int j = idx - 192 * 1024;
        Wob[j] = (bf16)Wo[j];
    } else {
        int j = idx - 262144;
        if (j < 512) { f32x4 z = {0.f, 0.f, 0.f, 0.f}; ((f32x4*)zpg)[j] = z; }
    }
}

// ================= K1: conv + split-bf16 MFMA in_proj + SSM + chunk-local scan =================
// 512 threads (8 waves), 2 blocks/CU. Block: 64t x 192n, BK=32, 32 chunks.
// Wave: 32t x 48n (wt = t-half, wn = n-quarter). W direct global->reg, 2-body prefetch.
// x: coalesced global->reg->LDS raw -> conv taps from LDS -> hi/lo xc tiles.
__global__ __launch_bounds__(512, 4) void k1_convproj(
    const float* __restrict__ x, const float* __restrict__ conv_w,
    const float* __restrict__ conv_b, const float* __restrict__ in_proj_b,
    const float* __restrict__ A_log,
    const bf16* __restrict__ Whg, const bf16* __restrict__ Wlg,
    const float* __restrict__ zpg,
    float* __restrict__ Yp, float* __restrict__ Zp,
    float* __restrict__ Psum, float* __restrict__ Ssum)
{
    __shared__ char smem[54272];
    // raw x f32 [68][32]: buf0 @0 (8704), buf1 @8704          (ends 17408)
    // xc hi bf16 [64][32] swz: buf0 @17408, buf1 @21504
    // xc lo:                   buf0 @25600, buf1 @29696       (ends 33792)
    // cwT tap-major f32 [4][1024] @33792 (16384)              (ends 50176)
    // cbl f32 [1024] @50176 (4096)                            (ends 54272)
    // epilogue overlay: res f32 [64][196] @0 (50176), part @50176 (4096)

    const int tid  = threadIdx.x;
    const int lane = tid & 63;
    const int wv   = tid >> 6;
    const int wt   = wv >> 2, wn = wv & 3;
    const int fr   = lane & 15, fs = lane >> 4;
    const int b    = blockIdx.x >> 6;
    const int tc   = blockIdx.x & 63;
    const int t0   = tc * 64;

    // staging mapping: thread -> (row srow 0..63, quad squad 0..7); tid<32 also halo rows 64..67
    const int srow  = tid >> 3, squad = tid & 7;
    const bool zrow = (t0 + srow == 4095);   // reference zero-pads last conv row

    const int g0 = t0 - 1 + srow;
    const float* rp0 = (g0 >= 0 && g0 < 4096)
                     ? x + ((size_t)b * 4096 + g0) * 1024 + squad * 4
                     : zpg + squad * 4;
    const float* rp1 = zpg + squad * 4;
    int hrow = 64;
    if (tid < 32) {
        hrow = 64 + (tid >> 3);
        int g1 = t0 - 1 + hrow;
        if (g1 < 4096) rp1 = x + ((size_t)b * 4096 + g1) * 1024 + squad * 4;
    }

    int aoff[2];
#pragma unroll
    for (int mi = 0; mi < 2; ++mi) {
        int r = wt * 32 + mi * 16 + fr;
        aoff[mi] = r * 64 + ((fs ^ SWZ(r)) << 4);
    }

    // W fragment base within a chunk
    const size_t wfo = (size_t)(wn * 48 + fr) * 32 + fs * 8;

    // ---- stage conv tables to LDS (tap-major) ----
    {
        float* cwT = (float*)(smem + 33792);
        float* cbl = (float*)(smem + 50176);
#pragma unroll
        for (int p = tid; p < 1024; p += 512) {
            f32x4 w4 = *(const f32x4*)&conv_w[p * 4];
            cwT[p]        = w4.x;
            cwT[1024 + p] = w4.y;
            cwT[2048 + p] = w4.z;
            cwT[3072 + p] = w4.w;
        }
        if (tid < 256) ((f32x4*)cbl)[tid] = ((const f32x4*)conv_b)[tid];
    }

    f32x4  xr0, xr1;
    bf16x8 wfa[6], wfb[6];
    f32x4  acc[2][3] = {};

    auto fetch_raw = [&](int c) {
        xr0 = *(const f32x4*)(rp0 + c * 32);
        if (tid < 32) xr1 = *(const f32x4*)(rp1 + c * 32);
    };
    auto raw_write = [&](int c) {
        char* rb = smem + (c & 1) * 8704;
        *(f32x4*)(rb + srow * 128 + squad * 16) = xr0;
        if (tid < 32) *(f32x4*)(rb + hrow * 128 + squad * 16) = xr1;
    };
    auto fetch_w = [&](int c, bf16x8 (&wf)[6]) {
        const bf16* ph = Whg + (size_t)c * 6144 + wfo;
        const bf16* pl = Wlg + (size_t)c * 6144 + wfo;
#pragma unroll
        for (int ni = 0; ni < 3; ++ni) {
            wf[ni]     = *(const bf16x8*)(ph + ni * 512);
            wf[3 + ni] = *(const bf16x8*)(pl + ni * 512);
        }
    };
    auto conv_chunk = [&](int cc) {          // rawbuf[cc&1] -> xcbuf[cc&1]
        const char* rb = smem + (cc & 1) * 8704;
        char* dh = smem + 17408 + (cc & 1) * 4096;
        char* dl = smem + 25600 + (cc & 1) * 4096;
        const float* cwT = (const float*)(smem + 33792);
        const float* cbl = (const float*)(smem + 50176);
        const int ch0 = cc * 32 + squad * 4;
        f32x4 v = *(const f32x4*)&cbl[ch0];
#pragma unroll
        for (int dt = 0; dt < 4; ++dt) {
            f32x4 w  = *(const f32x4*)&cwT[dt * 1024 + ch0];
            f32x4 xt = *(const f32x4*)(rb + (srow + dt) * 128 + squad * 16);
            v.x = fmaf(w.x, xt.x, v.x);
            v.y = fmaf(w.y, xt.y, v.y);
            v.z = fmaf(w.z, xt.z, v.z);
            v.w = fmaf(w.w, xt.w, v.w);
        }
        bf16x4 hi, lo;
#pragma unroll
        for (int j = 0; j < 4; ++j) {
            float vv = zrow ? 0.f : v[j];
            bf16 h = (bf16)vv;
            hi[j] = h;
            lo[j] = (bf16)(vv - (float)h);
        }
        int off = srow * 64 + ((((squad >> 1) ^ SWZ(srow)) & 3) << 4) + (squad & 1) * 8;
        *(bf16x4*)(dh + off) = hi;
        *(bf16x4*)(dl + off) = lo;
    };

    // ---- prologue ----
    fetch_raw(0);
    fetch_w(0, wfa);
    raw_write(0);
    fetch_raw(1);
    __syncthreads();                         // tables + raw0 visible
    conv_chunk(0);
    raw_write(1);
    fetch_raw(2);
    fetch_w(1, wfb);
    BAR_LDS();

    auto body = [&](int c, bf16x8 (&wf)[6]) {
        const int par = c & 1;
        const char* xh = smem + 17408 + par * 4096;
        const char* xl = smem + 25600 + par * 4096;
        bf16x8 ah0 = *(const bf16x8*)(xh + aoff[0]);
        bf16x8 ah1 = *(const bf16x8*)(xh + aoff[1]);
        bf16x8 al0 = *(const bf16x8*)(xl + aoff[0]);
        bf16x8 al1 = *(const bf16x8*)(xl + aoff[1]);
        __builtin_amdgcn_s_setprio(1);
#pragma unroll
        for (int ni = 0; ni < 3; ++ni) {
            bf16x8 bh = wf[ni], bl = wf[3 + ni];
            acc[0][ni] = __builtin_amdgcn_mfma_f32_16x16x32_bf16(ah0, bh, acc[0][ni], 0, 0, 0);
            acc[1][ni] = __builtin_amdgcn_mfma_f32_16x16x32_bf16(ah1, bh, acc[1][ni], 0, 0, 0);
            acc[0][ni] = __builtin_amdgcn_mfma_f32_16x16x32_bf16(al0, bh, acc[0][ni], 0, 0, 0);
            acc[1][ni] = __builtin_amdgcn_mfma_f32_16x16x32_bf16(al1, bh, acc[1][ni], 0, 0, 0);
            acc[0][ni] = __builtin_amdgcn_mfma_f32_16x16x32_bf16(ah0, bl, acc[0][ni], 0, 0, 0);
            acc[1][ni] = __builtin_amdgcn_mfma_f32_16x16x32_bf16(ah1, bl, acc[1][ni], 0, 0, 0);
        }
        __builtin_amdgcn_s_setprio(0);
        if (c + 2 < 32) fetch_w(c + 2, wf);  // 2-body distance
        if (c + 1 < 32) conv_chunk(c + 1);   // raw[(c+1)&1] -> xc[(c+1)&1]
        if (c + 2 < 32) raw_write(c + 2);    // xr (fetched last body) -> raw[c&1]
        if (c + 3 < 32) fetch_raw(c + 3);    // 1-body distance to raw_write
        BAR_LDS();
    };

#pragma unroll 1
    for (int cc = 0; cc < 32; cc += 2) {
        body(cc,     wfa);
        body(cc + 1, wfb);
    }

    // ---- epilogue: acc -> res[64][196], SSM elementwise + chunk-local scan ----
    float* res = (float*)smem;
#pragma unroll
    for (int mi = 0; mi < 2; ++mi)
#pragma unroll
        for (int ni = 0; ni < 3; ++ni) {
            int col = wn * 48 + ni * 16 + fr;
#pragma unroll
            for (int r = 0; r < 4; ++r)
                res[(wt * 32 + mi * 16 + fs * 4 + r) * 196 + col] = acc[mi][ni][r];
        }
    __syncthreads();

    float* part = (float*)(smem + 50176);    // [2][8][64]
    const int i  = lane;
    const int tg = wv;
    const float A  = -expf(A_log[i]);
    const float bd = in_proj_b[i];
    const float bB = 0.5f * (in_proj_b[64 + 2 * i] + in_proj_b[65 + 2 * i]);
    const float bC = 0.5f * (in_proj_b[192 + 2 * i] + in_proj_b[193 + 2 * i]);
    const bool tiny = fabsf(A) < EPS_C;
    float av[8], bv[8], cv[8];
#pragma unroll
    for (int r = 0; r < 8; ++r) {
        int t = tg * 8 + r;
        float d  = res[t * 196 + i] + bd;
        float Bm = res[t * 196 + 64 + i] + bB;
        float Cm = res[t * 196 + 128 + i] + bC;
        float delta = (d > 20.f) ? d : log1pf(expf(d));
        float dA = delta * A;
        float abar = expf(dA);
        float sc = tiny ? (1.f + dA * 0.5f + dA * dA * (1.f / 6.f)) : ((abar - 1.f) / A);
        av[r] = abar; bv[r] = sc * Bm; cv[r] = Cm;
    }
    float P = 1.f, S = 0.f;
#pragma unroll
    for (int r = 0; r < 8; ++r) { S = fmaf(av[r], S, bv[r]); P *= av[r]; }
    part[tg * 64 + i] = P;
    part[512 + tg * 64 + i] = S;
    __syncthreads();
    float h = 0.f, pp = 1.f;
#pragma unroll
    for (int g = 0; g < 7; ++g)
        if (g < tg) {
            float Pg = part[g * 64 + i], Sg = part[512 + g * 64 + i];
            h = fmaf(Pg, h, Sg);
            pp *= Pg;
        }
    size_t ob = ((size_t)b * 4096 + t0 + tg * 8) * 64 + i;
#pragma unroll
    for (int r = 0; r < 8; ++r) {
        h  = fmaf(av[r], h, bv[r]);          // chunk-local state
        pp *= av[r];                         // chunk-local prefix product
        Yp[ob + (size_t)r * 64] = cv[r] * h;
        Zp[ob + (size_t)r * 64] = cv[r] * pp;
    }
    if (tg == 7) {
        size_t o = ((size_t)b * 64 + tc) * 64 + i;
        Psum[o] = pp;
        Ssum[o] = h;
    }
}

// ================= K2: serial carry combine across 64 chunks =================
__global__ __launch_bounds__(64) void k2_scan2(const float* __restrict__ Psum,
    const float* __restrict__ Ssum, float* __restrict__ Carry)
{
    int b = blockIdx.x, i = threadIdx.x;
    float Pv[64], Sv[64];
#pragma unroll
    for (int c = 0; c < 64; ++c) {
        size_t o = ((size_t)(b * 64) + c) * 64 + i;
        Pv[c] = Psum[o]; Sv[c] = Ssum[o];
    }
    float h = 0.f;
#pragma unroll
    for (int c = 0; c < 64; ++c) {
        size_t o = ((size_t)(b * 64) + c) * 64 + i;
        Carry[o] = h;
        h = fmaf(Pv[c], h, Sv[c]);
    }
}

// ================= K3: y = Yp + Zp*carry, fused out_proj MFMA =================
// 512 threads (8 waves). Block = 64-t chunk; wave: 64t x 128n.
__global__ __launch_bounds__(512) void k3_scan_out(
    const float* __restrict__ Yp, const float* __restrict__ Zp,
    const float* __restrict__ Carry, const bf16* __restrict__ Wob,
    const float* __restrict__ bo, float* __restrict__ out)
{
    __shared__ char sm3[8192];               // [64 t][64 i] bf16, swizzled

    const int tid  = threadIdx.x;
    const int lane = tid & 63;
    const int wv   = tid >> 6;
    const int b    = blockIdx.x >> 6;
    const int ch   = blockIdx.x & 63;
    const int t0   = ch * 64;

    const int i = lane, tg = wv;
    float cr = Carry[((size_t)(b * 64) + ch) * 64 + i];
    size_t base = ((size_t)(b * 4096) + t0 + tg * 8) * 64 + i;
#pragma unroll
    for (int r = 0; r < 8; ++r) {
        float y = Yp[base + (size_t)r * 64] + Zp[base + (size_t)r * 64] * cr;
        int t = tg * 8 + r;
        int off = t * 128 + ((((i >> 3) ^ (t & 7)) & 7) << 4) + (i & 7) * 2;
        *(bf16*)(sm3 + off) = (bf16)y;
    }
    __syncthreads();

    const int fr = lane & 15, fs = lane >> 4;
    bf16x8 afr[4][2];
#pragma unroll
    for (int mi = 0; mi < 4; ++mi)
#pragma unroll
        for (int ks = 0; ks < 2; ++ks) {
            int row = mi * 16 + fr;
            int slot = ks * 4 + fs;
            int off = row * 128 + (((slot ^ (row & 7)) & 7) << 4);
            afr[mi][ks] = *(const bf16x8*)(sm3 + off);
        }
    const int n0 = wv * 128;
#pragma unroll
    for (int ni = 0; ni < 8; ++ni) {
        int col = n0 + ni * 16 + fr;
        bf16x8 b0 = *(const bf16x8*)(Wob + (size_t)col * 64 + fs * 8);
        bf16x8 b1 = *(const bf16x8*)(Wob + (size_t)col * 64 + 32 + fs * 8);
        float bias = bo[col];
#pragma unroll
        for (int mi = 0; mi < 4; ++mi) {
            f32x4 a = {};
            a = __builtin_amdgcn_mfma_f32_16x16x32_bf16(afr[mi][0], b0, a, 0, 0, 0);
            a = __builtin_amdgcn_mfma_f32_16x16x32_bf16(afr[mi][1], b1, a, 0, 0, 0);
#pragma unroll
            for (int r = 0; r < 4; ++r) {
                int t = mi * 16 + fs * 4 + r;
                out[((size_t)(b * 4096) + t0 + t) * 1024 + col] = a[r] + bias;
            }
        }
    }
}

extern "C" void kernel_launch(void* const* d_in, const int* in_sizes, int n_in,
                              void* d_out, int out_size, void* d_ws, size_t ws_size,
                              hipStream_t stream) {
    const float* x          = (const float*)d_in[0];
    const float* conv_w     = (const float*)d_in[1];
    const float* conv_b     = (const float*)d_in[2];
    const float* in_proj_w  = (const float*)d_in[3];
    const float* in_proj_b  = (const float*)d_in[4];
    const float* A_log      = (const float*)d_in[5];
    const float* out_proj_w = (const float*)d_in[6];
    const float* out_proj_b = (const float*)d_in[7];
    float* out = (float*)d_out;

    char* w = (char*)d_ws;
    bf16*  Whg  = (bf16*)w;                                   // 393216 B
    bf16*  Wlg  = (bf16*)(w + 393216);                        // 393216 B
    bf16*  Wob  = (bf16*)(w + 786432);                        // 131072 B
    float* Yp   = (float*)(w + 917504);                       // 8 MiB
    float* Zp   = (float*)(w + 917504 + 8388608);             // 8 MiB
    float* Psum = (float*)(w + 917504 + 2 * 8388608);         // 128 KiB used
    float* Ssum = (float*)(w + 917504 + 2 * 8388608 + 262144);
    float* Carry= (float*)(w + 917504 + 2 * 8388608 + 524288);
    float* zpg  = (float*)(w + 917504 + 2 * 8388608 + 786432); // 8 KiB zero page

    hipLaunchKernelGGL(k0_prep,     dim3(1025), dim3(256), 0, stream,
                       in_proj_w, out_proj_w, Whg, Wlg, Wob, zpg);
    hipLaunchKernelGGL(k1_convproj, dim3(512),  dim3(512), 0, stream,
                       x, conv_w, conv_b, in_proj_b, A_log, Whg, Wlg, zpg,
                       Yp, Zp, Psum, Ssum);
    hipLaunchKernelGGL(k2_scan2,    dim3(8),    dim3(64),  0, stream, Psum, Ssum, Carry);
    hipLaunchKernelGGL(k3_scan_out, dim3(512),  dim3(512), 0, stream,
                       Yp, Zp, Carry, Wob, out_proj_b, out);
}